// Round 18
// baseline (903.561 us; speedup 1.0000x reference)
//
#include <hip/hip_runtime.h>
#include <float.h>

#define WDIM 96
#define HW   9216
#define PH   98
#define IMG  (PH*PH)            // 9604
#define NPIXP (2*IMG)           // 19208 real padded pixels
#define NPIX 19328              // 151*128 compute pixels
#define GUARD 128
#define GPIX (NPIX + 2*GUARD)   // 19584
#define NKG_ACT 96              // kg planes per activation buffer (768/8)
#define MDIM 768                // padded cout
#define G3 824                  // conv3x3 kg rows (810 real; prefetch reads g<=815, zeros to 823)
#define G1 104                  // 1x1 kg rows (90 real; prefetch reads g<=95, zeros to 103)

typedef _Float16 f16;
typedef f16  f16x8 __attribute__((ext_vector_type(8)));
typedef f16  f16x4 __attribute__((ext_vector_type(4)));
typedef float f32x4 __attribute__((ext_vector_type(4)));
typedef float f32x16 __attribute__((ext_vector_type(16)));
typedef unsigned int u32;

// async global->LDS DMA, 16B per lane (wave-uniform LDS base + lane*16 dest; per-lane global src)
typedef __attribute__((address_space(1))) const u32 gu32;
typedef __attribute__((address_space(3))) u32 lu32;
__device__ __forceinline__ void gld16(const f16* g, f16* s)
{
    __builtin_amdgcn_global_load_lds((gu32*)g, (lu32*)s, 16, 0, 0);
}

// ---------------- prep: fold bias+BN into alpha/beta (padded to 768); l2-normalize protos ----
__global__ void prep_kernel(
    const float* __restrict__ cls_b,
    const float* __restrict__ g0, const float* __restrict__ b0,
    const float* __restrict__ rm0, const float* __restrict__ rv0,
    const float* __restrict__ p1b,
    const float* __restrict__ g1, const float* __restrict__ b1,
    const float* __restrict__ rm1, const float* __restrict__ rv1,
    const float* __restrict__ p2b,
    const float* __restrict__ protos,
    float* __restrict__ alpha, float* __restrict__ beta,
    float* __restrict__ protoN)
{
    __shared__ float red[4];
    if (blockIdx.x == 0) {
        for (int i = threadIdx.x; i < MDIM; i += blockDim.x) {
            if (i < 720) {
                float s0 = g0[i] * rsqrtf(rv0[i] + 1e-5f);
                alpha[i] = s0;
                beta[i]  = (cls_b[i] - rm0[i]) * s0 + b0[i];
                float s1 = g1[i] * rsqrtf(rv1[i] + 1e-5f);
                alpha[MDIM + i] = s1;
                beta[MDIM + i]  = (p1b[i] - rm1[i]) * s1 + b1[i];
                alpha[2*MDIM + i] = 1.0f;
                beta[2*MDIM + i]  = p2b[i];
            } else {
                alpha[i] = 0.f; beta[i] = 0.f;
                alpha[MDIM + i] = 0.f; beta[MDIM + i] = 0.f;
                alpha[2*MDIM + i] = 0.f; beta[2*MDIM + i] = 0.f;
            }
        }
    } else {
        int row = blockIdx.x - 1;              // 0..19
        const float* src = protos + row * 720;
        float s = 0.f;
        for (int i = threadIdx.x; i < 720; i += blockDim.x) { float v = src[i]; s += v * v; }
        #pragma unroll
        for (int off = 32; off > 0; off >>= 1) s += __shfl_down(s, off);
        int wave = threadIdx.x >> 6, lane = threadIdx.x & 63;
        if (lane == 0) red[wave] = s;
        __syncthreads();
        float tot = red[0] + red[1] + red[2] + red[3];
        float rn = 1.0f / fmaxf(sqrtf(tot), 1e-12f);
        for (int i = threadIdx.x; i < 720; i += blockDim.x)
            protoN[row * 720 + i] = src[i] * rn;
    }
}

// ---------------- w3 transform: dense per-thread chunk transpose (no LDS) -------------------
__global__ __launch_bounds__(256)
void w3trans_kernel(const float* __restrict__ w3,
                    f16* __restrict__ W3h, f16* __restrict__ W3l)
{
    int tid = blockIdx.x * blockDim.x + threadIdx.x;
    int kgl = tid / MDIM;
    int o   = tid - kgl * MDIM;
    if (kgl > 90) return;

    if (kgl == 90) {
        // zero pad rows g in [810, G3)
        f16x8 z = {0, 0, 0, 0, 0, 0, 0, 0};
        for (int g = 810; g < G3; ++g) {
            size_t off = ((size_t)g * MDIM + o) * 8;
            *(f16x8*)(W3h + off) = z;
            *(f16x8*)(W3l + off) = z;
        }
        return;
    }

    float buf[72];
    if (o < 720) {
        const float* src = w3 + (size_t)o * 6480 + kgl * 72;
        #pragma unroll
        for (int c = 0; c < 72; ++c) buf[c] = src[c];
    } else {
        #pragma unroll
        for (int c = 0; c < 72; ++c) buf[c] = 0.f;
    }

    #pragma unroll
    for (int s = 0; s < 9; ++s) {
        f16x8 hv, lv;
        #pragma unroll
        for (int c = 0; c < 8; ++c) {
            float v = buf[c * 9 + s];
            f16 h = (f16)v;
            hv[c] = h;
            lv[c] = (f16)(v - (float)h);
        }
        size_t off = ((size_t)(kgl * 9 + s) * MDIM + o) * 8;
        *(f16x8*)(W3h + off) = hv;
        *(f16x8*)(W3l + off) = lv;
    }
}

// ---------------- 1x1 weight transform (round-11 style: 32B-contiguous per-thread reads) ----
__global__ void w1trans_kernel(const float* __restrict__ w1a,
                               const float* __restrict__ w1b,
                               f16* __restrict__ W1ah, f16* __restrict__ W1al,
                               f16* __restrict__ W1bh, f16* __restrict__ W1bl)
{
    int tid = blockIdx.x * blockDim.x + threadIdx.x;
    const int N1 = G1 * MDIM;
    const float* src; f16 *dh, *dl; int g, o;
    if (tid < N1)            { g = tid / MDIM; o = tid - g * MDIM; src = w1a; dh = W1ah; dl = W1al; }
    else if (tid < 2 * N1)   { int u = tid - N1; g = u / MDIM; o = u - g * MDIM; src = w1b; dh = W1bh; dl = W1bl; }
    else return;

    float v[8];
    #pragma unroll
    for (int j = 0; j < 8; ++j) v[j] = 0.f;
    if (g < 90 && o < 720) {
        #pragma unroll
        for (int j = 0; j < 8; ++j)
            v[j] = src[(size_t)o * 720 + g * 8 + j];
    }
    f16x8 hv, lv;
    #pragma unroll
    for (int j = 0; j < 8; ++j) {
        f16 h = (f16)v[j];
        hv[j] = h;
        lv[j] = (f16)(v[j] - (float)h);
    }
    size_t off = ((size_t)g * MDIM + o) * 8;
    *(f16x8*)(dh + off) = hv;
    *(f16x8*)(dl + off) = lv;
}

// ---------------- upsample+concat -> split-fp16 K8-packed padded-image planes ---------------
__global__ void upsample_kernel(const float* __restrict__ f1,
                                const float* __restrict__ f2,
                                const float* __restrict__ f3,
                                const float* __restrict__ f4,
                                f16* __restrict__ Xhi, f16* __restrict__ Xlo)
{
    int tid = blockIdx.x * blockDim.x + threadIdx.x;
    if (tid >= 90 * GPIX) return;
    int kg = tid / GPIX;
    int gp = tid - kg * GPIX;
    int p  = gp - GUARD;
    float v[8];
    #pragma unroll
    for (int j = 0; j < 8; ++j) v[j] = 0.f;
    if (p >= 0 && p < NPIXP) {
        int b = p / IMG; int rem = p - b * IMG;
        int y = rem / PH; int x = rem - y * PH;
        if (y >= 1 && y <= 96 && x >= 1 && x <= 96) {
            int oy = y - 1, ox = x - 1;
            int c0 = kg * 8;
            if (c0 < 48) {
                #pragma unroll
                for (int j = 0; j < 8; ++j)
                    v[j] = f1[((size_t)(b * 48 + c0 + j)) * HW + oy * 96 + ox];
            } else {
                const float* src; int Cs, Hs, cb;
                if (c0 < 144)      { src = f2; Cs = 96;  Hs = 48; cb = c0 - 48; }
                else if (c0 < 336) { src = f3; Cs = 192; Hs = 24; cb = c0 - 144; }
                else               { src = f4; Cs = 384; Hs = 12; cb = c0 - 336; }
                float scale = (float)(Hs - 1) / 95.0f;
                float yf = oy * scale, xf = ox * scale;
                int y0 = (int)yf, x0 = (int)xf;
                float wy = yf - y0, wx = xf - x0;
                int y1 = min(y0 + 1, Hs - 1), x1 = min(x0 + 1, Hs - 1);
                #pragma unroll
                for (int j = 0; j < 8; ++j) {
                    const float* sb = src + (size_t)(b * Cs + cb + j) * Hs * Hs;
                    float v00 = sb[y0 * Hs + x0], v01 = sb[y0 * Hs + x1];
                    float v10 = sb[y1 * Hs + x0], v11 = sb[y1 * Hs + x1];
                    float r0 = v00 * (1.f - wy) + v10 * wy;
                    float r1 = v01 * (1.f - wy) + v11 * wy;
                    v[j] = r0 * (1.f - wx) + r1 * wx;
                }
            }
        }
    }
    f16x8 hv, lv;
    #pragma unroll
    for (int j = 0; j < 8; ++j) {
        f16 h = (f16)v[j];
        hv[j] = h;
        lv[j] = (f16)(v[j] - (float)h);
    }
    size_t off = (size_t)tid * 8;
    *(f16x8*)(Xhi + off) = hv;
    *(f16x8*)(Xlo + off) = lv;
}

// ---------------- split-fp16 MFMA implicit-GEMM conv v12: R11 schedule + 32x32x16 MFMA ------
// Round-18: ONLY change vs the verified R11 optimum (719us, conv3 445, MfmaUtil 61.5) is the
// MFMA shape: mfma_f32_32x32x16_f16 (measured ceiling 2382 vs 2075 TF, half the instruction
// count: 24/step vs 48). Fragment/epilogue layout is R3's CORRECTNESS-VERIFIED mapping:
//   A: lane row=l&31, k=(l>>5)*8+j  (g-row index = 2*kg + lk within the step's 4 g-rows)
//   B: symmetric; C/D: col=l&31, row=(reg&3)+8*(reg>>2)+4*(l>>5) -> f16x4 writes stay aligned.
// Sync skeleton, staging, vmcnt ledger all byte-identical to R11 (stage=4 + load_A=8 issues
// per BODY -> vmcnt(20)/vmcnt(12) unchanged). Register cost unchanged (acc 64, frags 32+32).
template<int NSTEP, int CONV3>
__global__ __launch_bounds__(256, 2)
void mfma_gemm(const f16* __restrict__ Whi, const f16* __restrict__ Wlo,
               const f16* __restrict__ Bhi_, const f16* __restrict__ Blo_,
               f16* __restrict__ Ohi, f16* __restrict__ Olo,
               const float* __restrict__ alpha, const float* __restrict__ beta,
               int relu)
{
    // [slot][g-row 4][hi/lo][col 128][k8]  -- 16KB per slot, B only
    __shared__ f16 sB[2][4][2][128][8];

    const int l = blockIdx.x;
    const int xcd = l & 7;
    const int j0 = l >> 3;                // 0..113
    const int ncol = xcd * 19 + j0 / 6;   // 19 n-columns per XCD band
    if (ncol >= 151) return;              // uniform early-out (no barriers executed)
    const int m0 = (j0 % 6) * 128;
    const int n0 = ncol * 128;

    const int t = threadIdx.x;
    const int lane = t & 63;
    const int wid = __builtin_amdgcn_readfirstlane(t >> 6);   // SGPR: wave-uniform
    const int wm = wid >> 1, wn = wid & 1;                    // scalar
    const int l31 = lane & 31, lk = lane >> 5;                // 32x32 row/col + k-group
    const int loff = lane * 8;                                // per-lane halves offset (staging)

    f32x16 acc[2][2];
    #pragma unroll
    for (int i = 0; i < 2; ++i)
        #pragma unroll
        for (int j = 0; j < 2; ++j)
            acc[i][j] = (f32x16){0.f,0.f,0.f,0.f,0.f,0.f,0.f,0.f,
                                 0.f,0.f,0.f,0.f,0.f,0.f,0.f,0.f};

    // A per-lane base (halves): g-row = 4*step + 2*kg + lk, row = m0 + wm*64 + mt*32 + l31
    const size_t aLane = ((size_t)lk * MDIM + m0 + wm * 64 + l31) * 8;
    const size_t aAdv  = (size_t)4 * MDIM * 8;     // halves per step
    const size_t aKg   = (size_t)2 * MDIM * 8;     // halves per kg

    auto stage_B = [&](int st, int slot) {
        const int g = 4 * st + wid;             // scalar
        long long brow;                          // scalar math (SALU)
        if (CONV3) {
            int gc = g > 809 ? 809 : g;
            int kgl = gc / 9;
            int s2 = gc - kgl * 9;
            brow = (long long)kgl * GPIX + (s2 / 3 - 1) * PH + (s2 % 3 - 1);
        } else {
            int gc = g > 89 ? 89 : g;           // clamp to REAL planes
            brow = (long long)gc * GPIX;
        }
        const f16* bh = Bhi_ + (brow + n0) * 8;  // uniform
        const f16* bl = Blo_ + (brow + n0) * 8;
        f16* dB = &sB[slot][wid][0][0][0];
        gld16(bh + loff,        dB);
        gld16(bh + 512 + loff,  dB + 512);
        gld16(bl + loff,        dB + 1024);
        gld16(bl + 512 + loff,  dB + 1536);
    };

    // a[kg*2+mt] = hi frag, a[4 + kg*2+mt] = lo frag
    auto load_A = [&](f16x8 (&a)[8], int st) {
        const f16* ah = Whi + aLane + (size_t)st * aAdv;
        const f16* al = Wlo + aLane + (size_t)st * aAdv;
        #pragma unroll
        for (int kg = 0; kg < 2; ++kg)
            #pragma unroll
            for (int mt = 0; mt < 2; ++mt) {
                a[kg*2 + mt]     = *(const f16x8*)(ah + kg * aKg + mt * 256);
                a[4 + kg*2 + mt] = *(const f16x8*)(al + kg * aKg + mt * 256);
            }
    };

    // b[kg*2+nt] = hi frag, b[4 + kg*2+nt] = lo frag
    auto read_B = [&](f16x8 (&b)[8], int c) {
        #pragma unroll
        for (int kg = 0; kg < 2; ++kg)
            #pragma unroll
            for (int nt = 0; nt < 2; ++nt) {
                b[kg*2 + nt]     = *(const f16x8*)&sB[c][2*kg + lk][0][wn*64 + nt*32 + l31][0];
                b[4 + kg*2 + nt] = *(const f16x8*)&sB[c][2*kg + lk][1][wn*64 + nt*32 + l31][0];
            }
    };

    // Dep-separated issue: 3 passes (hh, hl, lh) of 8 independent 32x32 MFMAs.
    auto compute = [&](f16x8 (&av)[8], f16x8 (&bv)[8]) {
        #pragma unroll
        for (int kg = 0; kg < 2; ++kg)
            #pragma unroll
            for (int mt = 0; mt < 2; ++mt)
                #pragma unroll
                for (int nt = 0; nt < 2; ++nt)
                    acc[mt][nt] = __builtin_amdgcn_mfma_f32_32x32x16_f16(av[kg*2+mt], bv[kg*2+nt], acc[mt][nt], 0, 0, 0);
        #pragma unroll
        for (int kg = 0; kg < 2; ++kg)
            #pragma unroll
            for (int mt = 0; mt < 2; ++mt)
                #pragma unroll
                for (int nt = 0; nt < 2; ++nt)
                    acc[mt][nt] = __builtin_amdgcn_mfma_f32_32x32x16_f16(av[kg*2+mt], bv[4+kg*2+nt], acc[mt][nt], 0, 0, 0);
        #pragma unroll
        for (int kg = 0; kg < 2; ++kg)
            #pragma unroll
            for (int mt = 0; mt < 2; ++mt)
                #pragma unroll
                for (int nt = 0; nt < 2; ++nt)
                    acc[mt][nt] = __builtin_amdgcn_mfma_f32_32x32x16_f16(av[4+kg*2+mt], bv[kg*2+nt], acc[mt][nt], 0, 0, 0);
    };

    f16x8 aP[8], aQ[8], bP[8], bQ[8];

    // SS = literal stage slot ((s+2)&1 == s&1); B(s+1) lives in slot SS^1.
#define BODY(S, SS, PA, PB, QA, QB)                                   \
    do {                                                              \
        stage_B((S) + 2, (SS));                                       \
        load_A(QA, (S) + 1);                                          \
        __builtin_amdgcn_sched_barrier(0);                            \
        asm volatile("s_waitcnt vmcnt(20)" ::: "memory");             \
        __builtin_amdgcn_s_barrier();                                 \
        read_B(QB, (SS) ^ 1);                                         \
        __builtin_amdgcn_sched_barrier(0);                            \
        __builtin_amdgcn_s_setprio(1);                                \
        compute(PA, PB);                                              \
        __builtin_amdgcn_s_setprio(0);                                \
        asm volatile("s_waitcnt lgkmcnt(0)" ::: "memory");            \
        __builtin_amdgcn_sched_barrier(0);                            \
        __builtin_amdgcn_s_barrier();                                 \
    } while (0)

    // prologue
    stage_B(0, 0);
    stage_B(1, 1);
    load_A(aP, 0);
    __builtin_amdgcn_sched_barrier(0);
    asm volatile("s_waitcnt vmcnt(12)" ::: "memory");   // B(0) landed (own)
    __builtin_amdgcn_s_barrier();                       // everyone's B(0) landed
    read_B(bP, 0);
    asm volatile("s_waitcnt lgkmcnt(0)" ::: "memory");
    __builtin_amdgcn_sched_barrier(0);
    __builtin_amdgcn_s_barrier();                       // all waves done reading slot0

    int s = 0;
    #pragma unroll 1
    for (; s + 1 < NSTEP; s += 2) {
        BODY(s,     0, aP, bP, aQ, bQ);
        BODY(s + 1, 1, aQ, bQ, aP, bP);
    }
    if (s < NSTEP)
        BODY(s, 0, aP, bP, aQ, bQ);   // odd tail: prefetch/read overreach is in-bounds+unused
#undef BODY

    // epilogue (R3-verified): C/D row = (reg&3) + 8*(reg>>2) + 4*lk; col = l31
    #pragma unroll
    for (int mt = 0; mt < 2; ++mt)
        #pragma unroll
        for (int nt = 0; nt < 2; ++nt) {
            const int P = n0 + wn * 64 + nt * 32 + l31;
            #pragma unroll
            for (int q = 0; q < 4; ++q) {
                const int rowb = m0 + wm * 64 + mt * 32 + q * 8 + lk * 4;
                const float4 a4 = *(const float4*)(alpha + rowb);
                const float4 b4 = *(const float4*)(beta + rowb);
                const size_t kg = rowb >> 3;
                const int sub = rowb & 7;
                float v0 = acc[mt][nt][q*4 + 0] * a4.x + b4.x;
                float v1 = acc[mt][nt][q*4 + 1] * a4.y + b4.y;
                float v2 = acc[mt][nt][q*4 + 2] * a4.z + b4.z;
                float v3 = acc[mt][nt][q*4 + 3] * a4.w + b4.w;
                if (relu) {
                    v0 = fmaxf(v0, 0.f); v1 = fmaxf(v1, 0.f);
                    v2 = fmaxf(v2, 0.f); v3 = fmaxf(v3, 0.f);
                }
                f16 h0 = (f16)v0, h1 = (f16)v1, h2 = (f16)v2, h3 = (f16)v3;
                f16x4 hv = {h0, h1, h2, h3};
                f16x4 lv = {(f16)(v0 - (float)h0), (f16)(v1 - (float)h1),
                            (f16)(v2 - (float)h2), (f16)(v3 - (float)h3)};
                size_t o = (kg * GPIX + P) * 8 + sub;
                *(f16x4*)(Ohi + o) = hv;
                *(f16x4*)(Olo + o) = lv;
            }
        }
}

// ---------------- head v2: 16 lanes/pixel, single pass over Y (values held in registers) -----
__global__ __launch_bounds__(256)
void head_kernel(const f16* __restrict__ Yhi, const f16* __restrict__ Ylo,  // at GUARD
                 const float* __restrict__ lng, const float* __restrict__ lnb,
                 const float* __restrict__ protoN,
                 const float* __restrict__ lmg, const float* __restrict__ lmb,
                 float* __restrict__ out)
{
    const int t = threadIdx.x;
    const int wv = t >> 6, lane = t & 63;
    const int pw = lane >> 4, sub = lane & 15;
    const int p = blockIdx.x * 16 + wv * 4 + pw;     // 0..18431
    const int b = p / HW; const int r = p - b * HW;
    const int y = r / 96; const int x = r - y * 96;
    const size_t P = (size_t)b * IMG + (y + 1) * PH + (x + 1);

    f16x8 xh[6], xl[6];
    float s1 = 0.f, s2 = 0.f;
    #pragma unroll
    for (int k = 0; k < 6; ++k) {
        int kg = sub + 16 * k;
        if (kg < 90) {
            xh[k] = *(const f16x8*)(Yhi + ((size_t)kg * GPIX + P) * 8);
            xl[k] = *(const f16x8*)(Ylo + ((size_t)kg * GPIX + P) * 8);
            #pragma unroll
            for (int j = 0; j < 8; ++j) {
                float v = (float)xh[k][j] + (float)xl[k][j];
                s1 += v; s2 += v * v;
            }
        }
    }
    #pragma unroll
    for (int m = 1; m < 16; m <<= 1) {
        s1 += __shfl_xor(s1, m);
        s2 += __shfl_xor(s2, m);
    }
    float mu  = s1 * (1.0f / 720.0f);
    float var = s2 * (1.0f / 720.0f) - mu * mu;
    float inv = rsqrtf(var + 1e-5f);

    float dots[20];
    #pragma unroll
    for (int q = 0; q < 20; ++q) dots[q] = 0.f;
    float nrm = 0.f;
    #pragma unroll
    for (int k = 0; k < 6; ++k) {
        int kg = sub + 16 * k;
        if (kg < 90) {
            const int c0 = kg * 8;
            #pragma unroll
            for (int j = 0; j < 8; ++j) {
                const int c = c0 + j;
                float v = ((float)xh[k][j] + (float)xl[k][j] - mu) * inv * lng[c] + lnb[c];
                nrm += v * v;
                #pragma unroll
                for (int q = 0; q < 20; ++q)
                    dots[q] = fmaf(v, protoN[q * 720 + c], dots[q]);
            }
        }
    }
    #pragma unroll
    for (int m = 1; m < 16; m <<= 1) {
        nrm += __shfl_xor(nrm, m);
        #pragma unroll
        for (int q = 0; q < 20; ++q) dots[q] += __shfl_xor(dots[q], m);
    }

    if (sub == 0) {
        float rn = 1.0f / fmaxf(sqrtf(nrm), 1e-12f);
        float m0v = -FLT_MAX, m1v = -FLT_MAX;
        #pragma unroll
        for (int q = 0; q < 10; ++q) m0v = fmaxf(m0v, dots[q]);
        #pragma unroll
        for (int q = 10; q < 20; ++q) m1v = fmaxf(m1v, dots[q]);
        m0v *= rn; m1v *= rn;
        float mu2 = 0.5f * (m0v + m1v);
        float dv  = m0v - mu2;
        float va  = dv * dv;
        float iv  = rsqrtf(va + 1e-5f);
        float o0 = (m0v - mu2) * iv * lmg[0] + lmb[0];
        float o1 = (m1v - mu2) * iv * lmg[1] + lmb[1];
        out[b * (2 * HW) + r]      = o0;
        out[b * (2 * HW) + HW + r] = o1;
    }
}

extern "C" void kernel_launch(void* const* d_in, const int* in_sizes, int n_in,
                              void* d_out, int out_size, void* d_ws, size_t ws_size,
                              hipStream_t stream)
{
    const float* feat1      = (const float*)d_in[0];
    const float* feat2      = (const float*)d_in[1];
    const float* feat3      = (const float*)d_in[2];
    const float* feat4      = (const float*)d_in[3];
    const float* cls_w      = (const float*)d_in[4];
    const float* cls_b      = (const float*)d_in[5];
    const float* cls_bn_g   = (const float*)d_in[6];
    const float* cls_bn_b   = (const float*)d_in[7];
    const float* cls_bn_rm  = (const float*)d_in[8];
    const float* cls_bn_rv  = (const float*)d_in[9];
    const float* proj_w1    = (const float*)d_in[10];
    const float* proj_b1    = (const float*)d_in[11];
    const float* proj_bn_g  = (const float*)d_in[12];
    const float* proj_bn_b  = (const float*)d_in[13];
    const float* proj_bn_rm = (const float*)d_in[14];
    const float* proj_bn_rv = (const float*)d_in[15];
    const float* proj_w2    = (const float*)d_in[16];
    const float* proj_b2    = (const float*)d_in[17];
    const float* ln_feat_g  = (const float*)d_in[18];
    const float* ln_feat_b  = (const float*)d_in[19];
    const float* ln_mask_g  = (const float*)d_in[20];
    const float* ln_mask_b  = (const float*)d_in[21];
    const float* protos     = (const float*)d_in[22];

    const size_t PLANEH = (size_t)NKG_ACT * GPIX * 8;    // 15,040,512 halves
    const size_t W3SZ   = (size_t)G3 * MDIM * 8;
    const size_t W1SZ   = (size_t)G1 * MDIM * 8;

    f16* Xhi  = (f16*)d_ws;
    f16* Xlo  = Xhi + PLANEH;
    f16* Yhi  = Xlo + PLANEH;
    f16* Ylo  = Yhi + PLANEH;
    f16* W3h  = Ylo + PLANEH;
    f16* W3l  = W3h + W3SZ;
    f16* W1ah = W3l + W3SZ;
    f16* W1al = W1ah + W1SZ;
    f16* W1bh = W1al + W1SZ;
    f16* W1bl = W1bh + W1SZ;
    float* alphas = (float*)(W1bl + W1SZ);
    float* betas  = alphas + 3 * MDIM;
    float* protoN = betas + 3 * MDIM;                    // [20][720]

    prep_kernel<<<21, 256, 0, stream>>>(cls_b, cls_bn_g, cls_bn_b, cls_bn_rm, cls_bn_rv,
                                        proj_b1, proj_bn_g, proj_bn_b, proj_bn_rm, proj_bn_rv,
                                        proj_b2, protos, alphas, betas, protoN);
    {
        int total = 91 * MDIM;                            // (kgl 0..90) x 768
        w3trans_kernel<<<(total + 255) / 256, 256, 0, stream>>>(cls_w, W3h, W3l);
    }
    {
        int total = 2 * G1 * MDIM;
        w1trans_kernel<<<(total + 255) / 256, 256, 0, stream>>>(proj_w1, proj_w2,
                                                                W1ah, W1al, W1bh, W1bl);
    }
    {
        int total = 90 * GPIX;
        upsample_kernel<<<(total + 255) / 256, 256, 0, stream>>>(feat1, feat2, feat3, feat4,
                                                                 Xhi, Xlo);
    }

    const size_t GOFF = (size_t)GUARD * 8;
    const int NBLK = 912;             // 8 XCD bands x 114 (19 ncols x 6 m-tiles); 6 no-op tails
    mfma_gemm<203, 1><<<NBLK, 256, 0, stream>>>(W3h, W3l, Xhi + GOFF, Xlo + GOFF,
                                                Yhi + GOFF, Ylo + GOFF,
                                                alphas, betas, 1);
    mfma_gemm<23, 0><<<NBLK, 256, 0, stream>>>(W1ah, W1al, Yhi + GOFF, Ylo + GOFF,
                                               Xhi + GOFF, Xlo + GOFF,
                                               alphas + MDIM, betas + MDIM, 1);
    mfma_gemm<23, 0><<<NBLK, 256, 0, stream>>>(W1bh, W1bl, Xhi + GOFF, Xlo + GOFF,
                                               Yhi + GOFF, Ylo + GOFF,
                                               alphas + 2 * MDIM, betas + 2 * MDIM, 0);

    head_kernel<<<HW * 2 / 16, 256, 0, stream>>>(Yhi + GOFF, Ylo + GOFF,
                                                 ln_feat_g, ln_feat_b, protoN,
                                                 ln_mask_g, ln_mask_b, (float*)d_out);
}

// Round 19
// 704.228 us; speedup vs baseline: 1.2831x; 1.2831x over previous
//
#include <hip/hip_runtime.h>
#include <float.h>

#define WDIM 96
#define HW   9216
#define PH   98
#define IMG  (PH*PH)            // 9604
#define NPIXP (2*IMG)           // 19208 real padded pixels
#define NPIX 19328              // 151*128 compute pixels
#define GUARD 128
#define GPIX (NPIX + 2*GUARD)   // 19584
#define NKG_ACT 96              // kg planes per activation buffer (768/8)
#define MDIM 768                // padded cout
#define G3 824                  // conv3x3 kg rows (810 real; prefetch reads g<=815, zeros to 823)
#define G1 104                  // 1x1 kg rows (90 real; prefetch reads g<=95, zeros to 103)

typedef _Float16 f16;
typedef f16  f16x8 __attribute__((ext_vector_type(8)));
typedef f16  f16x4 __attribute__((ext_vector_type(4)));
typedef float f32x4 __attribute__((ext_vector_type(4)));
typedef unsigned int u32;

// async global->LDS DMA, 16B per lane (wave-uniform LDS base + lane*16 dest; per-lane global src)
typedef __attribute__((address_space(1))) const u32 gu32;
typedef __attribute__((address_space(3))) u32 lu32;
__device__ __forceinline__ void gld16(const f16* g, f16* s)
{
    __builtin_amdgcn_global_load_lds((gu32*)g, (lu32*)s, 16, 0, 0);
}

// ---------------- prep: fold bias+BN into alpha/beta (padded to 768); l2-normalize protos ----
__global__ void prep_kernel(
    const float* __restrict__ cls_b,
    const float* __restrict__ g0, const float* __restrict__ b0,
    const float* __restrict__ rm0, const float* __restrict__ rv0,
    const float* __restrict__ p1b,
    const float* __restrict__ g1, const float* __restrict__ b1,
    const float* __restrict__ rm1, const float* __restrict__ rv1,
    const float* __restrict__ p2b,
    const float* __restrict__ protos,
    float* __restrict__ alpha, float* __restrict__ beta,
    float* __restrict__ protoN)
{
    __shared__ float red[4];
    if (blockIdx.x == 0) {
        for (int i = threadIdx.x; i < MDIM; i += blockDim.x) {
            if (i < 720) {
                float s0 = g0[i] * rsqrtf(rv0[i] + 1e-5f);
                alpha[i] = s0;
                beta[i]  = (cls_b[i] - rm0[i]) * s0 + b0[i];
                float s1 = g1[i] * rsqrtf(rv1[i] + 1e-5f);
                alpha[MDIM + i] = s1;
                beta[MDIM + i]  = (p1b[i] - rm1[i]) * s1 + b1[i];
                alpha[2*MDIM + i] = 1.0f;
                beta[2*MDIM + i]  = p2b[i];
            } else {
                alpha[i] = 0.f; beta[i] = 0.f;
                alpha[MDIM + i] = 0.f; beta[MDIM + i] = 0.f;
                alpha[2*MDIM + i] = 0.f; beta[2*MDIM + i] = 0.f;
            }
        }
    } else {
        int row = blockIdx.x - 1;              // 0..19
        const float* src = protos + row * 720;
        float s = 0.f;
        for (int i = threadIdx.x; i < 720; i += blockDim.x) { float v = src[i]; s += v * v; }
        #pragma unroll
        for (int off = 32; off > 0; off >>= 1) s += __shfl_down(s, off);
        int wave = threadIdx.x >> 6, lane = threadIdx.x & 63;
        if (lane == 0) red[wave] = s;
        __syncthreads();
        float tot = red[0] + red[1] + red[2] + red[3];
        float rn = 1.0f / fmaxf(sqrtf(tot), 1e-12f);
        for (int i = threadIdx.x; i < 720; i += blockDim.x)
            protoN[row * 720 + i] = src[i] * rn;
    }
}

// ---------------- w3 transform: dense per-thread chunk transpose (no LDS) -------------------
__global__ __launch_bounds__(256)
void w3trans_kernel(const float* __restrict__ w3,
                    f16* __restrict__ W3h, f16* __restrict__ W3l)
{
    int tid = blockIdx.x * blockDim.x + threadIdx.x;
    int kgl = tid / MDIM;
    int o   = tid - kgl * MDIM;
    if (kgl > 90) return;

    if (kgl == 90) {
        // zero pad rows g in [810, G3)
        f16x8 z = {0, 0, 0, 0, 0, 0, 0, 0};
        for (int g = 810; g < G3; ++g) {
            size_t off = ((size_t)g * MDIM + o) * 8;
            *(f16x8*)(W3h + off) = z;
            *(f16x8*)(W3l + off) = z;
        }
        return;
    }

    float buf[72];
    if (o < 720) {
        const float* src = w3 + (size_t)o * 6480 + kgl * 72;
        #pragma unroll
        for (int c = 0; c < 72; ++c) buf[c] = src[c];
    } else {
        #pragma unroll
        for (int c = 0; c < 72; ++c) buf[c] = 0.f;
    }

    #pragma unroll
    for (int s = 0; s < 9; ++s) {
        f16x8 hv, lv;
        #pragma unroll
        for (int c = 0; c < 8; ++c) {
            float v = buf[c * 9 + s];
            f16 h = (f16)v;
            hv[c] = h;
            lv[c] = (f16)(v - (float)h);
        }
        size_t off = ((size_t)(kgl * 9 + s) * MDIM + o) * 8;
        *(f16x8*)(W3h + off) = hv;
        *(f16x8*)(W3l + off) = lv;
    }
}

// ---------------- 1x1 weight transform (round-11 style: 32B-contiguous per-thread reads) ----
__global__ void w1trans_kernel(const float* __restrict__ w1a,
                               const float* __restrict__ w1b,
                               f16* __restrict__ W1ah, f16* __restrict__ W1al,
                               f16* __restrict__ W1bh, f16* __restrict__ W1bl)
{
    int tid = blockIdx.x * blockDim.x + threadIdx.x;
    const int N1 = G1 * MDIM;
    const float* src; f16 *dh, *dl; int g, o;
    if (tid < N1)            { g = tid / MDIM; o = tid - g * MDIM; src = w1a; dh = W1ah; dl = W1al; }
    else if (tid < 2 * N1)   { int u = tid - N1; g = u / MDIM; o = u - g * MDIM; src = w1b; dh = W1bh; dl = W1bl; }
    else return;

    float v[8];
    #pragma unroll
    for (int j = 0; j < 8; ++j) v[j] = 0.f;
    if (g < 90 && o < 720) {
        #pragma unroll
        for (int j = 0; j < 8; ++j)
            v[j] = src[(size_t)o * 720 + g * 8 + j];
    }
    f16x8 hv, lv;
    #pragma unroll
    for (int j = 0; j < 8; ++j) {
        f16 h = (f16)v[j];
        hv[j] = h;
        lv[j] = (f16)(v[j] - (float)h);
    }
    size_t off = ((size_t)g * MDIM + o) * 8;
    *(f16x8*)(dh + off) = hv;
    *(f16x8*)(dl + off) = lv;
}

// ---------------- upsample+concat -> split-fp16 K8-packed padded-image planes ---------------
__global__ void upsample_kernel(const float* __restrict__ f1,
                                const float* __restrict__ f2,
                                const float* __restrict__ f3,
                                const float* __restrict__ f4,
                                f16* __restrict__ Xhi, f16* __restrict__ Xlo)
{
    int tid = blockIdx.x * blockDim.x + threadIdx.x;
    if (tid >= 90 * GPIX) return;
    int kg = tid / GPIX;
    int gp = tid - kg * GPIX;
    int p  = gp - GUARD;
    float v[8];
    #pragma unroll
    for (int j = 0; j < 8; ++j) v[j] = 0.f;
    if (p >= 0 && p < NPIXP) {
        int b = p / IMG; int rem = p - b * IMG;
        int y = rem / PH; int x = rem - y * PH;
        if (y >= 1 && y <= 96 && x >= 1 && x <= 96) {
            int oy = y - 1, ox = x - 1;
            int c0 = kg * 8;
            if (c0 < 48) {
                #pragma unroll
                for (int j = 0; j < 8; ++j)
                    v[j] = f1[((size_t)(b * 48 + c0 + j)) * HW + oy * 96 + ox];
            } else {
                const float* src; int Cs, Hs, cb;
                if (c0 < 144)      { src = f2; Cs = 96;  Hs = 48; cb = c0 - 48; }
                else if (c0 < 336) { src = f3; Cs = 192; Hs = 24; cb = c0 - 144; }
                else               { src = f4; Cs = 384; Hs = 12; cb = c0 - 336; }
                float scale = (float)(Hs - 1) / 95.0f;
                float yf = oy * scale, xf = ox * scale;
                int y0 = (int)yf, x0 = (int)xf;
                float wy = yf - y0, wx = xf - x0;
                int y1 = min(y0 + 1, Hs - 1), x1 = min(x0 + 1, Hs - 1);
                #pragma unroll
                for (int j = 0; j < 8; ++j) {
                    const float* sb = src + (size_t)(b * Cs + cb + j) * Hs * Hs;
                    float v00 = sb[y0 * Hs + x0], v01 = sb[y0 * Hs + x1];
                    float v10 = sb[y1 * Hs + x0], v11 = sb[y1 * Hs + x1];
                    float r0 = v00 * (1.f - wy) + v10 * wy;
                    float r1 = v01 * (1.f - wy) + v11 * wy;
                    v[j] = r0 * (1.f - wx) + r1 * wx;
                }
            }
        }
    }
    f16x8 hv, lv;
    #pragma unroll
    for (int j = 0; j < 8; ++j) {
        f16 h = (f16)v[j];
        hv[j] = h;
        lv[j] = (f16)(v[j] - (float)h);
    }
    size_t off = (size_t)tid * 8;
    *(f16x8*)(Xhi + off) = hv;
    *(f16x8*)(Xlo + off) = lv;
}

// ---------------- split-fp16 MFMA implicit-GEMM conv v9 (R11 FINAL): B-only LDS -------------
// Round-19 FINAL: revert to the round-11 verified optimum (707/719us verified twice; conv3
// ~443us, MfmaUtil ~62, zero spill). Falsified levers this session: register ping-pong
// pipelines (compiler re-sinks), occupancy via launch_bounds (spill at 168-reg demand),
// dep-chain separation (neutral), phase stagger (neutral), SGPR scalarization (VALU down,
// dur flat), JIT-B 3-slot ring (spill + exposed ds_read), 32x32 MFMA shape (A-stream L2
// thrash: FETCH +165MB, -48%). Confirmed win: B-only LDS staging (halved LDS traffic,
// +10% over the A+B-staged dbuf).
// Structure: R4's counted-vmcnt sync skeleton; B LDS-staged 2 slots (32KB), fragments read
// ONE STEP AHEAD into bP/bQ; A direct global->register aP/aQ prefetched one step ahead,
// pinned with sched_barrier(0). LDS traffic 48KB/block-step.
// vmcnt ledger (12 issues/BODY: 4 B-stage + 8 A-load):
//   at BODY(s) wait, queue newest-first: A(s+1)[8] B(s+2)[4] A(s)[8] B(s+1)[4]
//   -> vmcnt(20) drains exactly B(s+1). Prologue: vmcnt(12) drains B(0).
template<int NSTEP, int CONV3>
__global__ __launch_bounds__(256, 2)
void mfma_gemm(const f16* __restrict__ Whi, const f16* __restrict__ Wlo,
               const f16* __restrict__ Bhi_, const f16* __restrict__ Blo_,
               f16* __restrict__ Ohi, f16* __restrict__ Olo,
               const float* __restrict__ alpha, const float* __restrict__ beta,
               int relu)
{
    // [slot][g-quad][hi/lo][col 128][k8]  -- 16KB per slot, B only
    __shared__ f16 sB[2][4][2][128][8];

    const int l = blockIdx.x;
    const int xcd = l & 7;
    const int j0 = l >> 3;                // 0..113
    const int ncol = xcd * 19 + j0 / 6;   // 19 n-columns per XCD band
    if (ncol >= 151) return;              // uniform early-out (no barriers executed)
    const int m0 = (j0 % 6) * 128;
    const int n0 = ncol * 128;

    const int t = threadIdx.x;
    const int lane = t & 63;
    const int wid = __builtin_amdgcn_readfirstlane(t >> 6);   // SGPR: wave-uniform
    const int wm = wid >> 1, wn = wid & 1;                    // scalar
    const int quad = lane >> 4, ln = lane & 15;               // divergent
    const int loff = lane * 8;                                // per-lane halves offset (staging)

    f32x4 acc[4][4];
    #pragma unroll
    for (int i = 0; i < 4; ++i)
        #pragma unroll
        for (int j = 0; j < 4; ++j)
            acc[i][j] = (f32x4){0.f, 0.f, 0.f, 0.f};

    // A per-lane base (halves): row = m0 + wm*64 + mt*16 + ln, g = 4*step + quad
    const size_t aLane = ((size_t)quad * MDIM + m0 + wm * 64 + ln) * 8;
    const size_t aAdv  = (size_t)4 * MDIM * 8;     // halves per step

    auto stage_B = [&](int st, int slot) {
        const int g = 4 * st + wid;             // scalar
        long long brow;                          // scalar math (SALU)
        if (CONV3) {
            int gc = g > 809 ? 809 : g;
            int kgl = gc / 9;
            int s2 = gc - kgl * 9;
            brow = (long long)kgl * GPIX + (s2 / 3 - 1) * PH + (s2 % 3 - 1);
        } else {
            int gc = g > 89 ? 89 : g;           // clamp to REAL planes
            brow = (long long)gc * GPIX;
        }
        const f16* bh = Bhi_ + (brow + n0) * 8;  // uniform
        const f16* bl = Blo_ + (brow + n0) * 8;
        f16* dB = &sB[slot][wid][0][0][0];
        gld16(bh + loff,        dB);
        gld16(bh + 512 + loff,  dB + 512);
        gld16(bl + loff,        dB + 1024);
        gld16(bl + 512 + loff,  dB + 1536);
    };

    auto load_A = [&](f16x8 (&a)[8], int st) {
        const f16* ah = Whi + aLane + (size_t)st * aAdv;
        const f16* al = Wlo + aLane + (size_t)st * aAdv;
        #pragma unroll
        for (int mt = 0; mt < 4; ++mt) {
            a[mt]     = *(const f16x8*)(ah + mt * 128);
            a[mt + 4] = *(const f16x8*)(al + mt * 128);
        }
    };

    auto read_B = [&](f16x8 (&b)[8], int c) {
        #pragma unroll
        for (int mt = 0; mt < 4; ++mt) {
            b[mt]     = *(const f16x8*)&sB[c][quad][0][wn * 64 + mt * 16 + ln][0];
            b[mt + 4] = *(const f16x8*)&sB[c][quad][1][wn * 64 + mt * 16 + ln][0];
        }
    };

    // Dep-separated issue: 3 passes of 16 independent MFMAs.
    auto compute = [&](f16x8 (&av)[8], f16x8 (&bv)[8]) {
        #pragma unroll
        for (int mt = 0; mt < 4; ++mt)
            #pragma unroll
            for (int nt = 0; nt < 4; ++nt)
                acc[mt][nt] = __builtin_amdgcn_mfma_f32_16x16x32_f16(av[mt], bv[nt], acc[mt][nt], 0, 0, 0);
        #pragma unroll
        for (int mt = 0; mt < 4; ++mt)
            #pragma unroll
            for (int nt = 0; nt < 4; ++nt)
                acc[mt][nt] = __builtin_amdgcn_mfma_f32_16x16x32_f16(av[mt], bv[nt + 4], acc[mt][nt], 0, 0, 0);
        #pragma unroll
        for (int mt = 0; mt < 4; ++mt)
            #pragma unroll
            for (int nt = 0; nt < 4; ++nt)
                acc[mt][nt] = __builtin_amdgcn_mfma_f32_16x16x32_f16(av[mt + 4], bv[nt], acc[mt][nt], 0, 0, 0);
    };

    f16x8 aP[8], aQ[8], bP[8], bQ[8];

    // SS = literal stage slot ((s+2)&1 == s&1); B(s+1) lives in slot SS^1.
    // compute step S from PA(=A(S)) x PB(=B(S), read last iter); read B(S+1) into QB now.
#define BODY(S, SS, PA, PB, QA, QB)                                   \
    do {                                                              \
        stage_B((S) + 2, (SS));                                       \
        load_A(QA, (S) + 1);                                          \
        __builtin_amdgcn_sched_barrier(0);                            \
        asm volatile("s_waitcnt vmcnt(20)" ::: "memory");             \
        __builtin_amdgcn_s_barrier();                                 \
        read_B(QB, (SS) ^ 1);                                         \
        __builtin_amdgcn_sched_barrier(0);                            \
        __builtin_amdgcn_s_setprio(1);                                \
        compute(PA, PB);                                              \
        __builtin_amdgcn_s_setprio(0);                                \
        asm volatile("s_waitcnt lgkmcnt(0)" ::: "memory");            \
        __builtin_amdgcn_sched_barrier(0);                            \
        __builtin_amdgcn_s_barrier();                                 \
    } while (0)

    // prologue
    stage_B(0, 0);
    stage_B(1, 1);
    load_A(aP, 0);
    __builtin_amdgcn_sched_barrier(0);
    asm volatile("s_waitcnt vmcnt(12)" ::: "memory");   // B(0) landed (own)
    __builtin_amdgcn_s_barrier();                       // everyone's B(0) landed
    read_B(bP, 0);
    asm volatile("s_waitcnt lgkmcnt(0)" ::: "memory");
    __builtin_amdgcn_sched_barrier(0);
    __builtin_amdgcn_s_barrier();                       // all waves done reading slot0

    int s = 0;
    #pragma unroll 1
    for (; s + 1 < NSTEP; s += 2) {
        BODY(s,     0, aP, bP, aQ, bQ);
        BODY(s + 1, 1, aQ, bQ, aP, bP);
    }
    if (s < NSTEP)
        BODY(s, 0, aP, bP, aQ, bQ);   // odd tail: prefetch/read overreach is in-bounds+unused
#undef BODY

    #pragma unroll
    for (int mt = 0; mt < 4; ++mt) {
        const int rowb = m0 + wm * 64 + mt * 16 + quad * 4;
        const float4 a4 = *(const float4*)(alpha + rowb);
        const float4 b4 = *(const float4*)(beta + rowb);
        const size_t kg = rowb >> 3;
        const int sub = rowb & 7;
        #pragma unroll
        for (int nt = 0; nt < 4; ++nt) {
            const int P = n0 + wn * 64 + nt * 16 + ln;
            float v0 = acc[mt][nt][0] * a4.x + b4.x;
            float v1 = acc[mt][nt][1] * a4.y + b4.y;
            float v2 = acc[mt][nt][2] * a4.z + b4.z;
            float v3 = acc[mt][nt][3] * a4.w + b4.w;
            if (relu) {
                v0 = fmaxf(v0, 0.f); v1 = fmaxf(v1, 0.f);
                v2 = fmaxf(v2, 0.f); v3 = fmaxf(v3, 0.f);
            }
            f16 h0 = (f16)v0, h1 = (f16)v1, h2 = (f16)v2, h3 = (f16)v3;
            f16x4 hv = {h0, h1, h2, h3};
            f16x4 lv = {(f16)(v0 - (float)h0), (f16)(v1 - (float)h1),
                        (f16)(v2 - (float)h2), (f16)(v3 - (float)h3)};
            size_t o = (kg * GPIX + P) * 8 + sub;
            *(f16x4*)(Ohi + o) = hv;
            *(f16x4*)(Olo + o) = lv;
        }
    }
}

// ---------------- head v2: 16 lanes/pixel, single pass over Y (values held in registers) -----
__global__ __launch_bounds__(256)
void head_kernel(const f16* __restrict__ Yhi, const f16* __restrict__ Ylo,  // at GUARD
                 const float* __restrict__ lng, const float* __restrict__ lnb,
                 const float* __restrict__ protoN,
                 const float* __restrict__ lmg, const float* __restrict__ lmb,
                 float* __restrict__ out)
{
    const int t = threadIdx.x;
    const int wv = t >> 6, lane = t & 63;
    const int pw = lane >> 4, sub = lane & 15;
    const int p = blockIdx.x * 16 + wv * 4 + pw;     // 0..18431
    const int b = p / HW; const int r = p - b * HW;
    const int y = r / 96; const int x = r - y * 96;
    const size_t P = (size_t)b * IMG + (y + 1) * PH + (x + 1);

    f16x8 xh[6], xl[6];
    float s1 = 0.f, s2 = 0.f;
    #pragma unroll
    for (int k = 0; k < 6; ++k) {
        int kg = sub + 16 * k;
        if (kg < 90) {
            xh[k] = *(const f16x8*)(Yhi + ((size_t)kg * GPIX + P) * 8);
            xl[k] = *(const f16x8*)(Ylo + ((size_t)kg * GPIX + P) * 8);
            #pragma unroll
            for (int j = 0; j < 8; ++j) {
                float v = (float)xh[k][j] + (float)xl[k][j];
                s1 += v; s2 += v * v;
            }
        }
    }
    #pragma unroll
    for (int m = 1; m < 16; m <<= 1) {
        s1 += __shfl_xor(s1, m);
        s2 += __shfl_xor(s2, m);
    }
    float mu  = s1 * (1.0f / 720.0f);
    float var = s2 * (1.0f / 720.0f) - mu * mu;
    float inv = rsqrtf(var + 1e-5f);

    float dots[20];
    #pragma unroll
    for (int q = 0; q < 20; ++q) dots[q] = 0.f;
    float nrm = 0.f;
    #pragma unroll
    for (int k = 0; k < 6; ++k) {
        int kg = sub + 16 * k;
        if (kg < 90) {
            const int c0 = kg * 8;
            #pragma unroll
            for (int j = 0; j < 8; ++j) {
                const int c = c0 + j;
                float v = ((float)xh[k][j] + (float)xl[k][j] - mu) * inv * lng[c] + lnb[c];
                nrm += v * v;
                #pragma unroll
                for (int q = 0; q < 20; ++q)
                    dots[q] = fmaf(v, protoN[q * 720 + c], dots[q]);
            }
        }
    }
    #pragma unroll
    for (int m = 1; m < 16; m <<= 1) {
        nrm += __shfl_xor(nrm, m);
        #pragma unroll
        for (int q = 0; q < 20; ++q) dots[q] += __shfl_xor(dots[q], m);
    }

    if (sub == 0) {
        float rn = 1.0f / fmaxf(sqrtf(nrm), 1e-12f);
        float m0v = -FLT_MAX, m1v = -FLT_MAX;
        #pragma unroll
        for (int q = 0; q < 10; ++q) m0v = fmaxf(m0v, dots[q]);
        #pragma unroll
        for (int q = 10; q < 20; ++q) m1v = fmaxf(m1v, dots[q]);
        m0v *= rn; m1v *= rn;
        float mu2 = 0.5f * (m0v + m1v);
        float dv  = m0v - mu2;
        float va  = dv * dv;
        float iv  = rsqrtf(va + 1e-5f);
        float o0 = (m0v - mu2) * iv * lmg[0] + lmb[0];
        float o1 = (m1v - mu2) * iv * lmg[1] + lmb[1];
        out[b * (2 * HW) + r]      = o0;
        out[b * (2 * HW) + HW + r] = o1;
    }
}

extern "C" void kernel_launch(void* const* d_in, const int* in_sizes, int n_in,
                              void* d_out, int out_size, void* d_ws, size_t ws_size,
                              hipStream_t stream)
{
    const float* feat1      = (const float*)d_in[0];
    const float* feat2      = (const float*)d_in[1];
    const float* feat3      = (const float*)d_in[2];
    const float* feat4      = (const float*)d_in[3];
    const float* cls_w      = (const float*)d_in[4];
    const float* cls_b      = (const float*)d_in[5];
    const float* cls_bn_g   = (const float*)d_in[6];
    const float* cls_bn_b   = (const float*)d_in[7];
    const float* cls_bn_rm  = (const float*)d_in[8];
    const float* cls_bn_rv  = (const float*)d_in[9];
    const float* proj_w1    = (const float*)d_in[10];
    const float* proj_b1    = (const float*)d_in[11];
    const float* proj_bn_g  = (const float*)d_in[12];
    const float* proj_bn_b  = (const float*)d_in[13];
    const float* proj_bn_rm = (const float*)d_in[14];
    const float* proj_bn_rv = (const float*)d_in[15];
    const float* proj_w2    = (const float*)d_in[16];
    const float* proj_b2    = (const float*)d_in[17];
    const float* ln_feat_g  = (const float*)d_in[18];
    const float* ln_feat_b  = (const float*)d_in[19];
    const float* ln_mask_g  = (const float*)d_in[20];
    const float* ln_mask_b  = (const float*)d_in[21];
    const float* protos     = (const float*)d_in[22];

    const size_t PLANEH = (size_t)NKG_ACT * GPIX * 8;    // 15,040,512 halves
    const size_t W3SZ   = (size_t)G3 * MDIM * 8;
    const size_t W1SZ   = (size_t)G1 * MDIM * 8;

    f16* Xhi  = (f16*)d_ws;
    f16* Xlo  = Xhi + PLANEH;
    f16* Yhi  = Xlo + PLANEH;
    f16* Ylo  = Yhi + PLANEH;
    f16* W3h  = Ylo + PLANEH;
    f16* W3l  = W3h + W3SZ;
    f16* W1ah = W3l + W3SZ;
    f16* W1al = W1ah + W1SZ;
    f16* W1bh = W1al + W1SZ;
    f16* W1bl = W1bh + W1SZ;
    float* alphas = (float*)(W1bl + W1SZ);
    float* betas  = alphas + 3 * MDIM;
    float* protoN = betas + 3 * MDIM;                    // [20][720]

    prep_kernel<<<21, 256, 0, stream>>>(cls_b, cls_bn_g, cls_bn_b, cls_bn_rm, cls_bn_rv,
                                        proj_b1, proj_bn_g, proj_bn_b, proj_bn_rm, proj_bn_rv,
                                        proj_b2, protos, alphas, betas, protoN);
    {
        int total = 91 * MDIM;                            // (kgl 0..90) x 768
        w3trans_kernel<<<(total + 255) / 256, 256, 0, stream>>>(cls_w, W3h, W3l);
    }
    {
        int total = 2 * G1 * MDIM;
        w1trans_kernel<<<(total + 255) / 256, 256, 0, stream>>>(proj_w1, proj_w2,
                                                                W1ah, W1al, W1bh, W1bl);
    }
    {
        int total = 90 * GPIX;
        upsample_kernel<<<(total + 255) / 256, 256, 0, stream>>>(feat1, feat2, feat3, feat4,
                                                                 Xhi, Xlo);
    }

    const size_t GOFF = (size_t)GUARD * 8;
    const int NBLK = 912;             // 8 XCD bands x 114 (19 ncols x 6 m-tiles); 6 no-op tails
    mfma_gemm<203, 1><<<NBLK, 256, 0, stream>>>(W3h, W3l, Xhi + GOFF, Xlo + GOFF,
                                                Yhi + GOFF, Ylo + GOFF,
                                                alphas, betas, 1);
    mfma_gemm<23, 0><<<NBLK, 256, 0, stream>>>(W1ah, W1al, Yhi + GOFF, Ylo + GOFF,
                                               Xhi + GOFF, Xlo + GOFF,
                                               alphas + MDIM, betas + MDIM, 1);
    mfma_gemm<23, 0><<<NBLK, 256, 0, stream>>>(W1bh, W1bl, Xhi + GOFF, Xlo + GOFF,
                                               Yhi + GOFF, Ylo + GOFF,
                                               alphas + 2 * MDIM, betas + 2 * MDIM, 0);

    head_kernel<<<HW * 2 / 16, 256, 0, stream>>>(Yhi + GOFF, Ylo + GOFF,
                                                 ln_feat_g, ln_feat_b, protoN,
                                                 ln_mask_g, ln_mask_b, (float*)d_out);
}